// Round 6
// baseline (1060.744 us; speedup 1.0000x reference)
//
#include <hip/hip_runtime.h>
#include <hip/hip_fp16.h>
#include <stdint.h>

// Problem: x[16,2048,512] f32, embed[4096,512] f32.
// encode: idx[n] = argmax_k -(||x_n||^2 - 2 x_n.e_k + ||e_k||^2)  (== argmax x.e - 0.5||e||^2)
// decode: quantize[n] = embed[idx[n]]
// d_out (float): [0,32768) = idx as float, [32768, +32768*512) = quantize.
//
// Two-stage: (1) approximate hi-f16 GEMM tracks per-row top-1 AND top-2;
// (2) rows with top-2 gap <= M_AMBIG are re-scored exactly (f64) over all
// codes. Gap >> approx-error for everything else, so argmax matches np.

typedef _Float16 f16;
typedef __attribute__((ext_vector_type(4))) _Float16 f16x4;
typedef __attribute__((ext_vector_type(8))) _Float16 f16x8;
typedef __attribute__((ext_vector_type(4))) float f32x4;

#define DDIM 512
#define KCODES 4096
#define NSPLIT 2
#define BM 256
#define BN 256
#define NCH ((KCODES / NSPLIT) / BN)   // 4 chunks per block
#define NSTEPS (NCH * (DDIM / 64))     // 32 iterations (BK=64 per iter)
#define PSTRIDE (NSPLIT * 2)           // per-row partial slots: (nsp, wc)
#define M_AMBIG 0.15f

__device__ __forceinline__ void gload_lds16(const void* g, void* l) {
  __builtin_amdgcn_global_load_lds(
      (const __attribute__((address_space(1))) void*)g,
      (__attribute__((address_space(3))) void*)l,
      16, 0, 0);
}

// -------- conversion: f32 -> hi f16, 4 elems/thread, grid-stride -------------
__global__ void convert_hi(const float* __restrict__ in, f16* __restrict__ hi, int n4) {
  int stride = gridDim.x * blockDim.x;
  for (int i = blockIdx.x * blockDim.x + threadIdx.x; i < n4; i += stride) {
    float4 v = ((const float4*)in)[i];
    f16x4 h;
    h[0] = (_Float16)v.x; h[1] = (_Float16)v.y;
    h[2] = (_Float16)v.z; h[3] = (_Float16)v.w;
    ((f16x4*)hi)[i] = h;
  }
}

// -------- e_sq: one wave per code row, f64 accumulation ----------------------
__global__ void esq_kernel(const float* __restrict__ e, float* __restrict__ esq) {
  int gw = (blockIdx.x * blockDim.x + threadIdx.x) >> 6;
  int lane = threadIdx.x & 63;
  if (gw >= KCODES) return;
  const float4* row = (const float4*)(e + (size_t)gw * DDIM);
  float4 a = row[lane * 2];
  float4 b = row[lane * 2 + 1];
  double s = (double)a.x * a.x + (double)a.y * a.y + (double)a.z * a.z + (double)a.w * a.w +
             (double)b.x * b.x + (double)b.y * b.y + (double)b.z * b.z + (double)b.w * b.w;
#pragma unroll
  for (int m = 32; m; m >>= 1) s += __shfl_xor(s, m, 64);
  if (lane == 0) esq[gw] = (float)s;
}

__global__ void zero_counter(int* c) { *c = 0; }

// -------- stage 1: approx f16 GEMM + running top-2 argmax --------------------
// grid = (nRows/256)*NSPLIT = 256 blocks (1/CU), 512 thr (8 waves 4x2).
// LDS per buffer (64 KiB): A0[256][32] @0, A1 @16K, B0 @32K, B1 @48K (BK=64
// as two 32-wide subtiles, preserving the conflict-free 64B-stride layout).
// R4-proven skeleton: STAGE(next) at top, one __syncthreads at bottom.
__global__ __launch_bounds__(512, 2) void vq_approx(
    const f16* __restrict__ Ah, const f16* __restrict__ Bh,
    const float* __restrict__ esq, float4* __restrict__ partials, int nRowBlocks) {
  __shared__ char lds[131072];               // 2 x 64 KiB double buffer
  __shared__ float esqLds[KCODES / NSPLIT];  // 8 KiB: 0.5*esq for this split

  int nwg = gridDim.x;
  int bid = blockIdx.x;
  int cpx = nwg >> 3;                       // nwg % 8 == 0
  int swz = (bid & 7) * cpx + (bid >> 3);   // XCD-aware swizzle (bijective)
  int nsp = swz / nRowBlocks;
  int brow = swz % nRowBlocks;
  int rowbase = brow * BM;

  int tid = threadIdx.x;
  int lane = tid & 63;
  int wv = tid >> 6;        // 0..7 waves, 4 (rows) x 2 (codes)
  int wr = wv >> 1, wc = wv & 1;
  int l15 = lane & 15, lg = lane >> 4;

  // fragment byte offsets within a [*][32] region (row stride 64 B)
  const int aoff = (wr * 64 + l15) * 64 + lg * 16;
  const int boff = (wc * 128 + l15) * 64 + lg * 16;

  int srow = tid >> 2;          // staging row (4 threads/row, 128 rows/round)
  int skoff = (tid & 3) * 8;    // f16 element offset within row
  const int codesPer = KCODES / NSPLIT;  // 2048

  const f16* aSrc = Ah + (size_t)(rowbase + srow) * DDIM + skoff;
  const f16* bBase = Bh + (size_t)(nsp * codesPer + srow) * DDIM + skoff;

  auto STAGE = [&](int buf, int ch, int kk) {  // 8 x global_load_lds (64 KiB)
    char* base = lds + buf * 65536 + wv * 1024;  // + lane*16 added by HW
    size_t bo = (size_t)(ch * BN) * DDIM + kk;
    gload_lds16(aSrc + kk, base);
    gload_lds16(aSrc + kk + (size_t)128 * DDIM, base + 8192);
    gload_lds16(aSrc + kk + 32, base + 16384);
    gload_lds16(aSrc + kk + 32 + (size_t)128 * DDIM, base + 16384 + 8192);
    gload_lds16(bBase + bo, base + 32768);
    gload_lds16(bBase + bo + (size_t)128 * DDIM, base + 32768 + 8192);
    gload_lds16(bBase + bo + 32, base + 49152);
    gload_lds16(bBase + bo + 32 + (size_t)128 * DDIM, base + 49152 + 8192);
  };

  float v1[16], v2[16];
  int i1[16];
#pragma unroll
  for (int t = 0; t < 16; ++t) { v1[t] = -3.4e38f; v2[t] = -3.4e38f; i1[t] = 0; }

  f32x4 acc[4][8];

  // prologue: fill esqLds (0.5*esq of this split) + stage step 0
  {
    float4 ev = ((const float4*)(esq + nsp * codesPer))[tid];
    ((float4*)esqLds)[tid] = make_float4(0.5f * ev.x, 0.5f * ev.y, 0.5f * ev.z, 0.5f * ev.w);
  }
  STAGE(0, 0, 0);
  __syncthreads();

#pragma unroll 1
  for (int s = 0; s < NSTEPS; ++s) {
    int cur = s & 1;
    int ch = s >> 3;
    int ns = s + 1;
    if (ns < NSTEPS) STAGE(cur ^ 1, ns >> 3, (ns & 7) * 64);

    if ((s & 7) == 0) {
#pragma unroll
      for (int i = 0; i < 4; ++i)
#pragma unroll
        for (int j = 0; j < 8; ++j) acc[i][j] = (f32x4){0.f, 0.f, 0.f, 0.f};
    }

    char* base = lds + cur * 65536;
    f16x8 af[4], bf[8];
    // k-subtile 0
#pragma unroll
    for (int i = 0; i < 4; ++i) af[i] = *(const f16x8*)(base + aoff + i * 1024);
#pragma unroll
    for (int j = 0; j < 8; ++j) bf[j] = *(const f16x8*)(base + 32768 + boff + j * 1024);
#pragma unroll
    for (int i = 0; i < 4; ++i)
#pragma unroll
      for (int j = 0; j < 8; ++j)
        acc[i][j] = __builtin_amdgcn_mfma_f32_16x16x32_f16(af[i], bf[j], acc[i][j], 0, 0, 0);
    // k-subtile 1
#pragma unroll
    for (int i = 0; i < 4; ++i) af[i] = *(const f16x8*)(base + 16384 + aoff + i * 1024);
#pragma unroll
    for (int j = 0; j < 8; ++j) bf[j] = *(const f16x8*)(base + 49152 + boff + j * 1024);
#pragma unroll
    for (int i = 0; i < 4; ++i)
#pragma unroll
      for (int j = 0; j < 8; ++j)
        acc[i][j] = __builtin_amdgcn_mfma_f32_16x16x32_f16(af[i], bf[j], acc[i][j], 0, 0, 0);

    if ((s & 7) == 7) {
      // chunk epilogue: registers + esqLds only; track top-1 AND top-2
      int cloc = ch * BN + wc * 128;
#pragma unroll
      for (int j = 0; j < 8; ++j) {
        float eh = esqLds[cloc + j * 16 + l15];
        int code = nsp * codesPer + cloc + j * 16 + l15;
#pragma unroll
        for (int i = 0; i < 4; ++i)
#pragma unroll
          for (int r = 0; r < 4; ++r) {
            float v = acc[i][j][r] - eh;
            int t = i * 4 + r;
            if (v > v1[t]) { v2[t] = v1[t]; v1[t] = v; i1[t] = code; }
            else if (v > v2[t]) v2[t] = v;
          }
      }
    }
    __syncthreads();
  }

  // butterfly top-2 merge over the 16 l15 lanes (same rows, different codes)
#pragma unroll
  for (int m = 1; m < 16; m <<= 1) {
#pragma unroll
    for (int t = 0; t < 16; ++t) {
      float ov1 = __shfl_xor(v1[t], m, 64);
      int oi1 = __shfl_xor(i1[t], m, 64);
      float ov2 = __shfl_xor(v2[t], m, 64);
      if (ov1 > v1[t] || (ov1 == v1[t] && oi1 < i1[t])) {
        v2[t] = fmaxf(v1[t], ov2);
        v1[t] = ov1; i1[t] = oi1;
      } else {
        v2[t] = fmaxf(v2[t], ov1);
      }
    }
  }
  if (l15 == 0) {
#pragma unroll
    for (int i = 0; i < 4; ++i)
#pragma unroll
      for (int r = 0; r < 4; ++r) {
        int row = rowbase + wr * 64 + i * 16 + lg * 4 + r;
        int t = i * 4 + r;
        partials[(size_t)row * PSTRIDE + nsp * 2 + wc] =
            make_float4(v1[t], (float)i1[t], v2[t], 0.f);
      }
  }
}

// -------- reduce partials, emit idx + ambiguous-row list ---------------------
__global__ void reduce_ambig(const float4* __restrict__ partials,
                             float* __restrict__ outIdx,
                             int* __restrict__ counter, int* __restrict__ list,
                             int nRows) {
  int row = blockIdx.x * blockDim.x + threadIdx.x;
  if (row >= nRows) return;
  float v1 = -3.4e38f, v2 = -3.4e38f;
  int i1 = 0x7fffffff;
#pragma unroll
  for (int s = 0; s < PSTRIDE; ++s) {
    float4 p = partials[(size_t)row * PSTRIDE + s];
    int pi = (int)p.y;
    if (p.x > v1 || (p.x == v1 && pi < i1)) {
      v2 = fmaxf(v1, p.z);
      v1 = p.x; i1 = pi;
    } else {
      v2 = fmaxf(v2, p.x);
    }
  }
  outIdx[row] = (float)i1;
  if (v1 - v2 <= M_AMBIG) {
    int pos = atomicAdd(counter, 1);
    list[pos] = row;
  }
}

// -------- exact f64 re-score of ambiguous rows -------------------------------
__global__ __launch_bounds__(256) void fixup_exact(
    const float* __restrict__ x, const float* __restrict__ embed,
    const int* __restrict__ counter, const int* __restrict__ list,
    float* __restrict__ outIdx) {
  __shared__ float xr[DDIM];
  __shared__ double sv[256];
  __shared__ int si[256];
  int tid = threadIdx.x;
  int cnt = *counter;
  for (int w = blockIdx.x; w < cnt; w += gridDim.x) {
    int row = list[w];
    for (int t = tid; t < DDIM; t += 256) xr[t] = x[(size_t)row * DDIM + t];
    __syncthreads();
    double best = -1e300;
    int bidx = 0;
#pragma unroll 1
    for (int j = 0; j < KCODES / 256; ++j) {
      int c = tid + j * 256;
      const float4* e4 = (const float4*)(embed + (size_t)c * DDIM);
      const float4* x4 = (const float4*)xr;
      double s = 0.0;
#pragma unroll 4
      for (int k = 0; k < DDIM / 4; ++k) {
        float4 ev = e4[k];
        float4 xv = x4[k];
        s += ((double)xv.x - 0.5 * (double)ev.x) * (double)ev.x;
        s += ((double)xv.y - 0.5 * (double)ev.y) * (double)ev.y;
        s += ((double)xv.z - 0.5 * (double)ev.z) * (double)ev.z;
        s += ((double)xv.w - 0.5 * (double)ev.w) * (double)ev.w;
      }
      if (s > best || (s == best && c < bidx)) { best = s; bidx = c; }
    }
    sv[tid] = best; si[tid] = bidx;
    __syncthreads();
    for (int m = 128; m; m >>= 1) {
      if (tid < m) {
        if (sv[tid + m] > sv[tid] || (sv[tid + m] == sv[tid] && si[tid + m] < si[tid])) {
          sv[tid] = sv[tid + m]; si[tid] = si[tid + m];
        }
      }
      __syncthreads();
    }
    if (tid == 0) outIdx[row] = (float)si[0];
    __syncthreads();
  }
}

// -------- decode gather ------------------------------------------------------
__global__ void decode(const float* __restrict__ embed, const float* __restrict__ outIdx,
                       float* __restrict__ outQ, int nRows) {
  int gw = (blockIdx.x * blockDim.x + threadIdx.x) >> 6;
  int lane = threadIdx.x & 63;
  if (gw >= nRows) return;
  int bi = (int)outIdx[gw];
  const float4* src = (const float4*)(embed + (size_t)bi * DDIM);
  float4* dst = (float4*)(outQ + (size_t)gw * DDIM);
  dst[lane] = src[lane];
  dst[lane + 64] = src[lane + 64];
}

extern "C" void kernel_launch(void* const* d_in, const int* in_sizes, int n_in,
                              void* d_out, int out_size, void* d_ws, size_t ws_size,
                              hipStream_t stream) {
  const float* x = (const float*)d_in[0];
  const float* embed = (const float*)d_in[1];
  int nX = in_sizes[0];        // 16*2048*512
  int nRows = nX / DDIM;       // 32768
  int nRowBlocks = nRows / BM; // 128

  float* out = (float*)d_out;
  float* outIdx = out;
  float* outQ = out + nRows;

  size_t szA = (size_t)nRows * DDIM * sizeof(f16);           // 32 MiB
  size_t szB = (size_t)KCODES * DDIM * sizeof(f16);          // 4 MiB
  size_t szEsq = (size_t)KCODES * sizeof(float);             // 16 KiB
  size_t szPart = (size_t)nRows * PSTRIDE * sizeof(float4);  // 2 MiB
  size_t szList = (size_t)nRows * sizeof(int);               // 128 KiB

  char* ws = (char*)d_ws;
  f16 *Ah, *Bh;
  float* esq;
  float4* parts;
  int* counter;
  int* list;
  size_t needFull = szA + szB + szEsq + szPart + szList + 256;
  if (ws_size >= needFull) {
    Ah = (f16*)ws;
    Bh = (f16*)(ws + szA);
    esq = (float*)(ws + szA + szB);
    parts = (float4*)(ws + szA + szB + szEsq);
    list = (int*)(ws + szA + szB + szEsq + szPart);
    counter = (int*)(ws + szA + szB + szEsq + szPart + szList);
  } else {
    // quantize region of d_out (64 MiB) holds Ah; overwritten by decode at end
    Ah = (f16*)outQ;
    Bh = (f16*)ws;
    esq = (float*)(ws + szB);
    parts = (float4*)(ws + szB + szEsq);
    list = (int*)(ws + szB + szEsq + szPart);
    counter = (int*)(ws + szB + szEsq + szPart + szList);
  }

  int n4x = nX / 4;
  int n4e = in_sizes[1] / 4;
  hipLaunchKernelGGL(convert_hi, dim3(2048), dim3(256), 0, stream, x, Ah, n4x);
  hipLaunchKernelGGL(convert_hi, dim3((n4e + 255) / 256), dim3(256), 0, stream, embed, Bh, n4e);
  hipLaunchKernelGGL(esq_kernel, dim3(KCODES / 4), dim3(256), 0, stream, embed, esq);
  hipLaunchKernelGGL(zero_counter, dim3(1), dim3(1), 0, stream, counter);
  hipLaunchKernelGGL(vq_approx, dim3(nRowBlocks * NSPLIT), dim3(512), 0, stream,
                     Ah, Bh, esq, parts, nRowBlocks);
  hipLaunchKernelGGL(reduce_ambig, dim3(nRows / 256), dim3(256), 0, stream,
                     parts, outIdx, counter, list, nRows);
  hipLaunchKernelGGL(fixup_exact, dim3(256), dim3(256), 0, stream,
                     x, embed, counter, list, outIdx);
  hipLaunchKernelGGL(decode, dim3(nRows / 4), dim3(256), 0, stream,
                     embed, outIdx, outQ, nRows);
}

// Round 7
// 795.718 us; speedup vs baseline: 1.3331x; 1.3331x over previous
//
#include <hip/hip_runtime.h>
#include <hip/hip_fp16.h>
#include <stdint.h>

// Problem: x[16,2048,512] f32, embed[4096,512] f32.
// encode: idx[n] = argmax_k (x.e_k - 0.5||e_k||^2); decode: embed[idx].
// d_out (float): [0,32768) = idx, [32768,+32768*512) = quantize.
//
// Stage 1 (vq_main): hi-f16 MFMA GEMM, A-tile LDS-RESIDENT (staged once,
// kills the 8x A re-read = 512 MB that bounded R6), B streamed dbuf with
// counted vmcnt. Tracks per-row top-3 (idx for top-2).
// Stage 2: gap> BAND certain; else exact f64 on {i1,i2} (fixupA); if even
// v1-v3<=BAND (rare ~20 rows), full exact scan (fixupB, wave-parallel).

typedef _Float16 f16;
typedef __attribute__((ext_vector_type(4))) _Float16 f16x4;
typedef __attribute__((ext_vector_type(8))) _Float16 f16x8;
typedef __attribute__((ext_vector_type(4))) float f32x4;

#define DDIM 512
#define KCODES 4096
#define BM 128
#define BN 256                       // codes per chunk
#define NCHUNK (KCODES / BN)         // 16
#define NSTEP (NCHUNK * (DDIM / 32)) // 256 k-steps
#define BAND 0.25f
#define CAPB 4096

__device__ __forceinline__ void gload_lds16(const void* g, void* l) {
  __builtin_amdgcn_global_load_lds(
      (const __attribute__((address_space(1))) void*)g,
      (__attribute__((address_space(3))) void*)l,
      16, 0, 0);
}

// -------- conversion: f32 -> hi f16 ------------------------------------------
__global__ void convert_hi(const float* __restrict__ in, f16* __restrict__ hi, int n4) {
  int stride = gridDim.x * blockDim.x;
  for (int i = blockIdx.x * blockDim.x + threadIdx.x; i < n4; i += stride) {
    float4 v = ((const float4*)in)[i];
    f16x4 h;
    h[0] = (_Float16)v.x; h[1] = (_Float16)v.y;
    h[2] = (_Float16)v.z; h[3] = (_Float16)v.w;
    ((f16x4*)hi)[i] = h;
  }
}

// -------- esqh: 0.5*||e||^2, one wave per code row, f64 accumulation ---------
__global__ void esq_kernel(const float* __restrict__ e, float* __restrict__ esqh) {
  int gw = (blockIdx.x * blockDim.x + threadIdx.x) >> 6;
  int lane = threadIdx.x & 63;
  if (gw >= KCODES) return;
  const float4* row = (const float4*)(e + (size_t)gw * DDIM);
  float4 a = row[lane * 2];
  float4 b = row[lane * 2 + 1];
  double s = (double)a.x * a.x + (double)a.y * a.y + (double)a.z * a.z + (double)a.w * a.w +
             (double)b.x * b.x + (double)b.y * b.y + (double)b.z * b.z + (double)b.w * b.w;
#pragma unroll
  for (int m = 32; m; m >>= 1) s += __shfl_xor(s, m, 64);
  if (lane == 0) esqh[gw] = (float)(0.5 * s);
}

__global__ void zero2(int* c) { c[0] = 0; c[1] = 0; }

// -------- stage 1: A-LDS-resident f16 GEMM + top-3 argmax --------------------
// grid = nRows/128 = 256 blocks (1/CU), 256 thr (4 waves x 32 rows).
// LDS: A[128][512] swizzled @0 (128K), B dbuf [256][32] swz @131072 (2x16K).
__global__ __launch_bounds__(256, 1) void vq_main(
    const f16* __restrict__ Ah, const f16* __restrict__ Bh,
    const float* __restrict__ esqh, float* __restrict__ outIdx,
    int4* __restrict__ listA, int* __restrict__ listB, int* __restrict__ cnts) {
  __shared__ char lds[163840];
  const int tid = threadIdx.x;
  const int lane = tid & 63;
  const int wv = tid >> 6;
  const int l15 = lane & 15, lg = lane >> 4;
  const int rowbase = blockIdx.x * BM;

  const int swzA = (l15 & 7) << 4;                       // A row&7 == l15&7
  const int swzB = ((l15 & 3) ^ ((l15 >> 2) & 3)) << 4;  // B row-derived, j-invariant
  const int boffB = l15 * 64 + ((lg * 16) ^ swzB);

  // ---- prologue: A[128][512] -> LDS once (source pre-XORed, linear dest) ----
#pragma unroll 1
  for (int it = 0; it < 32; ++it) {
    int row = it * 4 + (tid >> 6);
    int scolb = ((tid & 63) * 16) ^ ((row & 7) << 4);
    gload_lds16(Ah + (size_t)(rowbase + row) * DDIM + (scolb >> 1),
                lds + it * 4096 + wv * 1024);
  }
  {  // stage B chunk0/kstep0 into buf 0
    char* dbase = lds + 131072 + wv * 1024;
#pragma unroll
    for (int r = 0; r < 4; ++r) {
      int row = r * 64 + (tid >> 2);
      int sw = ((row & 3) ^ ((row >> 2) & 3)) << 4;
      int scol = (((tid & 3) * 16) ^ sw) >> 1;
      gload_lds16(Bh + (size_t)row * DDIM + scol, dbase + r * 4096);
    }
  }
  __syncthreads();  // single full drain

  f32x4 acc[2][16];
  float esqv[16];
  float v1[8], v2[8], v3[8];
  int i1[8], i2[8];
#pragma unroll
  for (int t = 0; t < 8; ++t) { v1[t] = v2[t] = v3[t] = -3.4e38f; i1[t] = i2[t] = 0; }

#pragma unroll 1
  for (int s = 0; s < NSTEP; ++s) {
    const int ch = s >> 4, ks = s & 15, cur = s & 1;
    if (ks == 0) {
#pragma unroll
      for (int j = 0; j < 16; ++j) esqv[j] = esqh[ch * 256 + j * 16 + l15];
#pragma unroll
      for (int i = 0; i < 2; ++i)
#pragma unroll
        for (int j = 0; j < 16; ++j) acc[i][j] = (f32x4){0.f, 0.f, 0.f, 0.f};
    }
    if (s + 1 < NSTEP) {  // stage next kstep into other buffer
      const int ns = s + 1, chn = ns >> 4, ksn = ns & 15;
      char* dbase = lds + 131072 + (cur ^ 1) * 16384 + wv * 1024;
#pragma unroll
      for (int r = 0; r < 4; ++r) {
        int row = r * 64 + (tid >> 2);
        int sw = ((row & 3) ^ ((row >> 2) & 3)) << 4;
        int scol = (((tid & 3) * 16) ^ sw) >> 1;
        gload_lds16(Bh + (size_t)(chn * BN + row) * DDIM + ksn * 32 + scol,
                    dbase + r * 4096);
      }
      asm volatile("s_waitcnt vmcnt(4)" ::: "memory");  // current data in; 4 in flight
    } else {
      asm volatile("s_waitcnt vmcnt(0)" ::: "memory");
    }
    __builtin_amdgcn_s_barrier();

    const int acol = (ks * 64 + lg * 16) ^ swzA;
    f16x8 af0 = *(const f16x8*)(lds + (wv * 32 + l15) * 1024 + acol);
    f16x8 af1 = *(const f16x8*)(lds + (wv * 32 + 16 + l15) * 1024 + acol);
    const char* bb = lds + 131072 + cur * 16384;
#pragma unroll
    for (int j = 0; j < 16; ++j) {
      f16x8 bf = *(const f16x8*)(bb + j * 1024 + boffB);
      acc[0][j] = __builtin_amdgcn_mfma_f32_16x16x32_f16(af0, bf, acc[0][j], 0, 0, 0);
      acc[1][j] = __builtin_amdgcn_mfma_f32_16x16x32_f16(af1, bf, acc[1][j], 0, 0, 0);
    }
    if (ks == 15) {  // chunk epilogue: regs only
#pragma unroll
      for (int j = 0; j < 16; ++j) {
        int code = ch * 256 + j * 16 + l15;
        float eh = esqv[j];
#pragma unroll
        for (int i = 0; i < 2; ++i)
#pragma unroll
          for (int r = 0; r < 4; ++r) {
            float v = acc[i][j][r] - eh;
            int t = i * 4 + r;
            if (v > v1[t]) { v3[t] = v2[t]; v2[t] = v1[t]; i2[t] = i1[t]; v1[t] = v; i1[t] = code; }
            else if (v > v2[t]) { v3[t] = v2[t]; v2[t] = v; i2[t] = code; }
            else if (v > v3[t]) v3[t] = v;
          }
      }
    }
    __builtin_amdgcn_s_barrier();
  }

  // butterfly top-3 merge over the 16 l15 lanes (same rows, different codes)
#pragma unroll
  for (int m = 1; m < 16; m <<= 1) {
#pragma unroll
    for (int t = 0; t < 8; ++t) {
      float ov1 = __shfl_xor(v1[t], m, 64);
      int oi1 = __shfl_xor(i1[t], m, 64);
      float ov2 = __shfl_xor(v2[t], m, 64);
      int oi2 = __shfl_xor(i2[t], m, 64);
      float ov3 = __shfl_xor(v3[t], m, 64);
      if (ov1 > v1[t] || (ov1 == v1[t] && oi1 < i1[t])) {
        if (v1[t] > ov2 || (v1[t] == ov2 && i1[t] < oi2)) {
          v3[t] = fmaxf(ov2, v2[t]);
          v2[t] = v1[t]; i2[t] = i1[t];
        } else {
          v3[t] = fmaxf(v1[t], ov3);
          v2[t] = ov2; i2[t] = oi2;
        }
        v1[t] = ov1; i1[t] = oi1;
      } else {
        if (ov1 > v2[t] || (ov1 == v2[t] && oi1 < i2[t])) {
          v3[t] = fmaxf(v2[t], ov2);
          v2[t] = ov1; i2[t] = oi1;
        } else {
          v3[t] = fmaxf(ov1, v3[t]);
        }
      }
    }
  }
  if (l15 == 0) {
#pragma unroll
    for (int t = 0; t < 8; ++t) {
      int i = t >> 2, r = t & 3;
      int row = rowbase + wv * 32 + i * 16 + lg * 4 + r;
      outIdx[row] = (float)i1[t];
      if (v1[t] - v2[t] <= BAND) {
        int pos = atomicAdd(&cnts[0], 1);
        listA[pos] = make_int4(row, i1[t], i2[t], 0);
      }
      if (v1[t] - v3[t] <= BAND) {
        int pos = atomicAdd(&cnts[1], 1);
        listB[pos] = row;
      }
    }
  }
}

#define DOT8(s, xa, xb, ea, eb)                                    \
  s += ((double)xa.x - 0.5 * (double)ea.x) * (double)ea.x;         \
  s += ((double)xa.y - 0.5 * (double)ea.y) * (double)ea.y;         \
  s += ((double)xa.z - 0.5 * (double)ea.z) * (double)ea.z;         \
  s += ((double)xa.w - 0.5 * (double)ea.w) * (double)ea.w;         \
  s += ((double)xb.x - 0.5 * (double)eb.x) * (double)eb.x;         \
  s += ((double)xb.y - 0.5 * (double)eb.y) * (double)eb.y;         \
  s += ((double)xb.z - 0.5 * (double)eb.z) * (double)eb.z;         \
  s += ((double)xb.w - 0.5 * (double)eb.w) * (double)eb.w;

// -------- fixupA: exact f64 re-score of {i1,i2}, one wave per entry ----------
__global__ void fixupA(const float* __restrict__ x, const float* __restrict__ embed,
                       const int* __restrict__ cnts, const int4* __restrict__ listA,
                       float* __restrict__ outIdx) {
  int gw = (blockIdx.x * blockDim.x + threadIdx.x) >> 6;
  int lane = threadIdx.x & 63;
  int nw = (gridDim.x * blockDim.x) >> 6;
  int n = cnts[0];
  for (int u = gw; u < n; u += nw) {
    int4 e = listA[u];
    const float4* xp = (const float4*)(x + (size_t)e.x * DDIM);
    float4 xa = xp[lane * 2], xb = xp[lane * 2 + 1];
    double d0, d1;
    {
      const float4* ep = (const float4*)(embed + (size_t)e.y * DDIM);
      float4 ea = ep[lane * 2], eb = ep[lane * 2 + 1];
      double s = 0.0; DOT8(s, xa, xb, ea, eb);
#pragma unroll
      for (int m = 32; m; m >>= 1) s += __shfl_xor(s, m, 64);
      d0 = s;
    }
    {
      const float4* ep = (const float4*)(embed + (size_t)e.z * DDIM);
      float4 ea = ep[lane * 2], eb = ep[lane * 2 + 1];
      double s = 0.0; DOT8(s, xa, xb, ea, eb);
#pragma unroll
      for (int m = 32; m; m >>= 1) s += __shfl_xor(s, m, 64);
      d1 = s;
    }
    if (lane == 0) {
      int best = (d1 > d0 || (d1 == d0 && e.z < e.y)) ? e.z : e.y;
      outIdx[e.x] = (float)best;
    }
  }
}

// -------- fixupB: full exact scan for rare rows; 8 blocks/row + merge --------
__global__ __launch_bounds__(256) void fixupB(
    const float* __restrict__ x, const float* __restrict__ embed,
    const int* __restrict__ cnts, const int* __restrict__ listB,
    double2* __restrict__ fbParts) {
  __shared__ double sv[4];
  __shared__ int si[4];
  int tid = threadIdx.x, lane = tid & 63, wv = tid >> 6;
  int nB = cnts[1]; if (nB > CAPB) nB = CAPB;
  for (int u = blockIdx.x; u < nB * 8; u += gridDim.x) {
    int entry = u >> 3, oct = u & 7;
    int row = listB[entry];
    const float4* xp = (const float4*)(x + (size_t)row * DDIM);
    float4 xa = xp[lane * 2], xb = xp[lane * 2 + 1];
    double bv = -1e300; int bi = 0;
    int cbase = oct * 512 + wv * 128;
#pragma unroll 1
    for (int k = 0; k < 128; ++k) {
      int c = cbase + k;
      const float4* ep = (const float4*)(embed + (size_t)c * DDIM);
      float4 ea = ep[lane * 2], eb = ep[lane * 2 + 1];
      double s = 0.0; DOT8(s, xa, xb, ea, eb);
#pragma unroll
      for (int m = 32; m; m >>= 1) s += __shfl_xor(s, m, 64);
      if (s > bv) { bv = s; bi = c; }
    }
    if (lane == 0) { sv[wv] = bv; si[wv] = bi; }
    __syncthreads();
    if (tid == 0) {
      double b = sv[0]; int bidx = si[0];
#pragma unroll
      for (int w = 1; w < 4; ++w)
        if (sv[w] > b || (sv[w] == b && si[w] < bidx)) { b = sv[w]; bidx = si[w]; }
      fbParts[entry * 8 + oct] = make_double2(b, (double)bidx);
    }
    __syncthreads();
  }
}

__global__ void fixupB2(const int* __restrict__ cnts, const int* __restrict__ listB,
                        const double2* __restrict__ fbParts, float* __restrict__ outIdx) {
  int nB = cnts[1]; if (nB > CAPB) nB = CAPB;
  for (int e = threadIdx.x; e < nB; e += blockDim.x) {
    double bv = -1e300; int bi = 0;
#pragma unroll
    for (int q = 0; q < 8; ++q) {
      double2 p = fbParts[e * 8 + q];
      int pi = (int)p.y;
      if (p.x > bv || (p.x == bv && pi < bi)) { bv = p.x; bi = pi; }
    }
    outIdx[listB[e]] = (float)bi;
  }
}

// -------- decode gather ------------------------------------------------------
__global__ void decode(const float* __restrict__ embed, const float* __restrict__ outIdx,
                       float* __restrict__ outQ, int nRows) {
  int gw = (blockIdx.x * blockDim.x + threadIdx.x) >> 6;
  int lane = threadIdx.x & 63;
  if (gw >= nRows) return;
  int bi = (int)outIdx[gw];
  const float4* src = (const float4*)(embed + (size_t)bi * DDIM);
  float4* dst = (float4*)(outQ + (size_t)gw * DDIM);
  dst[lane] = src[lane];
  dst[lane + 64] = src[lane + 64];
}

extern "C" void kernel_launch(void* const* d_in, const int* in_sizes, int n_in,
                              void* d_out, int out_size, void* d_ws, size_t ws_size,
                              hipStream_t stream) {
  const float* x = (const float*)d_in[0];
  const float* embed = (const float*)d_in[1];
  int nX = in_sizes[0];        // 16*2048*512
  int nRows = nX / DDIM;       // 32768
  int nRowBlocks = nRows / BM; // 256

  float* out = (float*)d_out;
  float* outIdx = out;
  float* outQ = out + nRows;

  size_t szA = (size_t)nRows * DDIM * sizeof(f16);    // 32 MiB
  size_t szB = (size_t)KCODES * DDIM * sizeof(f16);   // 4 MiB
  size_t szEsq = (size_t)KCODES * sizeof(float);      // 16 KiB
  size_t szLA = (size_t)nRows * sizeof(int4);         // 512 KiB
  size_t szLB = (size_t)nRows * sizeof(int);          // 128 KiB
  size_t szFB = (size_t)CAPB * 8 * sizeof(double2);   // 512 KiB

  char* ws = (char*)d_ws;
  f16 *Ah, *Bh;
  float* esqh;
  int4* listA;
  int* listB;
  double2* fbParts;
  int* cnts;
  size_t needFull = szA + szB + szEsq + szLA + szLB + szFB + 64;
  if (ws_size >= needFull) {
    Ah = (f16*)ws;
    Bh = (f16*)(ws + szA);
    esqh = (float*)(ws + szA + szB);
    listA = (int4*)(ws + szA + szB + szEsq);
    listB = (int*)(ws + szA + szB + szEsq + szLA);
    fbParts = (double2*)(ws + szA + szB + szEsq + szLA + szLB);
    cnts = (int*)(ws + szA + szB + szEsq + szLA + szLB + szFB);
  } else {
    // quantize region of d_out (64 MiB) holds Ah; decode overwrites it at end
    Ah = (f16*)outQ;
    Bh = (f16*)ws;
    esqh = (float*)(ws + szB);
    listA = (int4*)(ws + szB + szEsq);
    listB = (int*)(ws + szB + szEsq + szLA);
    fbParts = (double2*)(ws + szB + szEsq + szLA + szLB);
    cnts = (int*)(ws + szB + szEsq + szLA + szLB + szFB);
  }

  int n4x = nX / 4;
  int n4e = in_sizes[1] / 4;
  hipLaunchKernelGGL(convert_hi, dim3(2048), dim3(256), 0, stream, x, Ah, n4x);
  hipLaunchKernelGGL(convert_hi, dim3((n4e + 255) / 256), dim3(256), 0, stream, embed, Bh, n4e);
  hipLaunchKernelGGL(esq_kernel, dim3(KCODES / 4), dim3(256), 0, stream, embed, esqh);
  hipLaunchKernelGGL(zero2, dim3(1), dim3(1), 0, stream, cnts);
  hipLaunchKernelGGL(vq_main, dim3(nRowBlocks), dim3(256), 0, stream,
                     Ah, Bh, esqh, outIdx, listA, listB, cnts);
  hipLaunchKernelGGL(fixupA, dim3(256), dim3(256), 0, stream, x, embed, cnts, listA, outIdx);
  hipLaunchKernelGGL(fixupB, dim3(1024), dim3(256), 0, stream, x, embed, cnts, listB, fbParts);
  hipLaunchKernelGGL(fixupB2, dim3(1), dim3(256), 0, stream, cnts, listB, fbParts, outIdx);
  hipLaunchKernelGGL(decode, dim3(nRows / 4), dim3(256), 0, stream,
                     embed, outIdx, outQ, nRows);
}